// Round 1
// baseline (1295.571 us; speedup 1.0000x reference)
//
#include <hip/hip_runtime.h>
#include <hip/hip_bf16.h>
#include <math.h>

#define N_TOK 4096
#define C_DIM 1024
#define E_NUM 16
#define I_DIM 256

#define BM 64
#define BN 64
#define KC 16
#define LDP 68   // padded LDS row stride in floats (k-major, pad=4 -> 2-way max on r/w)

__device__ __forceinline__ float gelu_exact(float v) {
    return 0.5f * v * (1.0f + erff(v * 0.70710678118654752f));
}

// ---------------- K1: gate ----------------
// one block per token: x-norm, sim col norms (redundant per block, trivial),
// 16 scores, mask count.
__global__ __launch_bounds__(256) void smk_gate(
    const float* __restrict__ x,      // [N, C]
    const float* __restrict__ sim,    // [C, E]
    const float* __restrict__ thr,    // [1]
    float* __restrict__ scores,       // [N, E]
    float* __restrict__ kpt)          // [N] (float-promoted ints)
{
    __shared__ __align__(16) float xs[C_DIM];
    __shared__ float red[256];
    __shared__ float pm[16][17];
    __shared__ float ssq[E_NUM];
    __shared__ float mk[E_NUM];

    const int t   = blockIdx.x;
    const int tid = threadIdx.x;

    // load x row (float4), stash in LDS, sum of squares
    float4 xv = *(const float4*)&x[(size_t)t * C_DIM + tid * 4];
    *(float4*)&xs[tid * 4] = xv;
    red[tid] = xv.x*xv.x + xv.y*xv.y + xv.z*xv.z + xv.w*xv.w;
    __syncthreads();
    for (int s = 128; s > 0; s >>= 1) {
        if (tid < s) red[tid] += red[tid + s];
        __syncthreads();
    }
    const float nx = sqrtf(red[0]);

    // per-column sim sumsq + dot(x, sim[:,e]); thread group (tid>>4) walks c, e=tid&15
    float pss = 0.f, pdot = 0.f;
    const int e16 = tid & 15;
    for (int c = (tid >> 4); c < C_DIM; c += 16) {
        float sv = sim[c * E_NUM + e16];
        pss  = fmaf(sv, sv, pss);
        pdot = fmaf(xs[c], sv, pdot);
    }
    pm[tid >> 4][e16] = pss;
    __syncthreads();
    if (tid < 16) {
        float s1 = 0.f;
        #pragma unroll
        for (int g = 0; g < 16; ++g) s1 += pm[g][tid];
        ssq[tid] = s1;
    }
    __syncthreads();
    pm[tid >> 4][e16] = pdot;
    __syncthreads();
    if (tid < 16) {
        float s2 = 0.f;
        #pragma unroll
        for (int g = 0; g < 16; ++g) s2 += pm[g][tid];
        float inv_nx = 1.f / fmaxf(nx, 1e-12f);
        float inv_ns = 1.f / fmaxf(sqrtf(ssq[tid]), 1e-12f);
        float sc = s2 * inv_nx * inv_ns;
        scores[(size_t)t * E_NUM + tid] = sc;
        mk[tid] = (sc > thr[0]) ? 1.f : 0.f;
    }
    __syncthreads();
    if (tid == 0) {
        float k = 0.f;
        #pragma unroll
        for (int e = 0; e < E_NUM; ++e) k += mk[e];
        kpt[t] = k;
    }
}

// ---------------- K2: H = gelu(X @ W1[e]^T) ----------------
// 64x64 tile, KC=16, fp32 4x4 micro-tile.
// H index: Hbase(+e*I if eh==E) [ t * (eh*I) + i ]
__global__ __launch_bounds__(256) void smk_ffn1(
    const float* __restrict__ X,    // [N, C]
    const float* __restrict__ W1,   // [E, I, C]
    float* __restrict__ H,
    int eh, int ez0)
{
    const int e  = blockIdx.z + ez0;
    const int t0 = blockIdx.x * BM;
    const int i0 = blockIdx.y * BN;

    const float* Ap = X + (size_t)t0 * C_DIM;
    const float* Bp = W1 + ((size_t)e * I_DIM + i0) * C_DIM;

    __shared__ __align__(16) float As[KC][LDP];
    __shared__ __align__(16) float Bs[KC][LDP];

    const int tid = threadIdx.x;
    const int tx = tid & 15, ty = tid >> 4;
    const int lm = tid >> 2;            // 0..63
    const int lk = (tid & 3) * 4;       // 0,4,8,12

    float acc[4][4] = {};

    for (int k0 = 0; k0 < C_DIM; k0 += KC) {
        float4 av = *(const float4*)&Ap[(size_t)lm * C_DIM + k0 + lk];
        float4 bv = *(const float4*)&Bp[(size_t)lm * C_DIM + k0 + lk];
        __syncthreads();
        As[lk + 0][lm] = av.x; As[lk + 1][lm] = av.y;
        As[lk + 2][lm] = av.z; As[lk + 3][lm] = av.w;
        Bs[lk + 0][lm] = bv.x; Bs[lk + 1][lm] = bv.y;
        Bs[lk + 2][lm] = bv.z; Bs[lk + 3][lm] = bv.w;
        __syncthreads();
        #pragma unroll
        for (int k = 0; k < KC; ++k) {
            float4 a4 = *(const float4*)&As[k][ty * 4];
            float4 b4 = *(const float4*)&Bs[k][tx * 4];
            float a[4] = {a4.x, a4.y, a4.z, a4.w};
            float b[4] = {b4.x, b4.y, b4.z, b4.w};
            #pragma unroll
            for (int i = 0; i < 4; ++i)
                #pragma unroll
                for (int j = 0; j < 4; ++j)
                    acc[i][j] = fmaf(a[i], b[j], acc[i][j]);
        }
    }

    const size_t hrow = (size_t)eh * I_DIM;
    float* Hp = H + ((eh == E_NUM) ? (size_t)e * I_DIM : 0);
    #pragma unroll
    for (int i = 0; i < 4; ++i) {
        int t = t0 + ty * 4 + i;
        float4 o;
        o.x = gelu_exact(acc[i][0]);
        o.y = gelu_exact(acc[i][1]);
        o.z = gelu_exact(acc[i][2]);
        o.w = gelu_exact(acc[i][3]);
        *(float4*)&Hp[(size_t)t * hrow + i0 + tx * 4] = o;
    }
}

// ---------------- K3: eo[:,e,:] = mask * (H @ W2[e]^T) ----------------
__global__ __launch_bounds__(256) void smk_ffn2(
    const float* __restrict__ Hst,
    const float* __restrict__ W2,     // [E, C, I]
    const float* __restrict__ scores, // [N, E]
    const float* __restrict__ thr,
    float* __restrict__ eo,           // [N, E, C]
    int eh, int ez0)
{
    const int e  = blockIdx.z + ez0;
    const int t0 = blockIdx.x * BM;
    const int c0 = blockIdx.y * BN;

    const size_t hrow = (size_t)eh * I_DIM;
    const float* Ap = Hst + ((eh == E_NUM) ? (size_t)e * I_DIM : 0) + (size_t)t0 * hrow;
    const float* Bp = W2 + ((size_t)e * C_DIM + c0) * I_DIM;

    __shared__ __align__(16) float As[KC][LDP];
    __shared__ __align__(16) float Bs[KC][LDP];

    const int tid = threadIdx.x;
    const int tx = tid & 15, ty = tid >> 4;
    const int lm = tid >> 2;
    const int lk = (tid & 3) * 4;

    float acc[4][4] = {};

    for (int k0 = 0; k0 < I_DIM; k0 += KC) {
        float4 av = *(const float4*)&Ap[(size_t)lm * hrow + k0 + lk];
        float4 bv = *(const float4*)&Bp[(size_t)lm * I_DIM + k0 + lk];
        __syncthreads();
        As[lk + 0][lm] = av.x; As[lk + 1][lm] = av.y;
        As[lk + 2][lm] = av.z; As[lk + 3][lm] = av.w;
        Bs[lk + 0][lm] = bv.x; Bs[lk + 1][lm] = bv.y;
        Bs[lk + 2][lm] = bv.z; Bs[lk + 3][lm] = bv.w;
        __syncthreads();
        #pragma unroll
        for (int k = 0; k < KC; ++k) {
            float4 a4 = *(const float4*)&As[k][ty * 4];
            float4 b4 = *(const float4*)&Bs[k][tx * 4];
            float a[4] = {a4.x, a4.y, a4.z, a4.w};
            float b[4] = {b4.x, b4.y, b4.z, b4.w};
            #pragma unroll
            for (int i = 0; i < 4; ++i)
                #pragma unroll
                for (int j = 0; j < 4; ++j)
                    acc[i][j] = fmaf(a[i], b[j], acc[i][j]);
        }
    }

    const float th = thr[0];
    #pragma unroll
    for (int i = 0; i < 4; ++i) {
        int t = t0 + ty * 4 + i;
        float m = (scores[(size_t)t * E_NUM + e] > th) ? 1.f : 0.f;
        float4 o;
        o.x = acc[i][0] * m; o.y = acc[i][1] * m;
        o.z = acc[i][2] * m; o.w = acc[i][3] * m;
        *(float4*)&eo[((size_t)t * E_NUM + e) * C_DIM + c0 + tx * 4] = o;
    }
}

// ---------------- K4: final = sum_e eo ----------------
__global__ __launch_bounds__(256) void smk_combine(
    const float* __restrict__ eo, float* __restrict__ fin)
{
    size_t idx = ((size_t)blockIdx.x * 256 + threadIdx.x) * 4;
    size_t t = idx / C_DIM;
    int c = (int)(idx % C_DIM);
    const float* p = eo + (size_t)t * E_NUM * C_DIM + c;
    float4 s = {0.f, 0.f, 0.f, 0.f};
    #pragma unroll
    for (int e = 0; e < E_NUM; ++e) {
        float4 v = *(const float4*)&p[(size_t)e * C_DIM];
        s.x += v.x; s.y += v.y; s.z += v.z; s.w += v.w;
    }
    *(float4*)&fin[idx] = s;
}

extern "C" void kernel_launch(void* const* d_in, const int* in_sizes, int n_in,
                              void* d_out, int out_size, void* d_ws, size_t ws_size,
                              hipStream_t stream) {
    const float* x   = (const float*)d_in[0];
    const float* sim = (const float*)d_in[1];
    const float* thr = (const float*)d_in[2];
    const float* W1  = (const float*)d_in[3];
    const float* W2  = (const float*)d_in[4];

    float* out    = (float*)d_out;
    float* fin    = out;                                   // 4,194,304
    float* scores = out + (size_t)N_TOK * C_DIM;           // 65,536
    float* eo     = scores + (size_t)N_TOK * E_NUM;        // 67,108,864
    float* kpt    = eo + (size_t)N_TOK * E_NUM * C_DIM;    // 4,096

    smk_gate<<<N_TOK, 256, 0, stream>>>(x, sim, thr, scores, kpt);

    const size_t needH = (size_t)N_TOK * E_NUM * I_DIM * sizeof(float); // 64 MB
    if (ws_size >= needH) {
        float* H = (float*)d_ws;
        dim3 g1(N_TOK / BM, I_DIM / BN, E_NUM);
        smk_ffn1<<<g1, 256, 0, stream>>>(x, W1, H, E_NUM, 0);
        dim3 g2(N_TOK / BM, C_DIM / BN, E_NUM);
        smk_ffn2<<<g2, 256, 0, stream>>>(H, W2, scores, thr, eo, E_NUM, 0);
    } else {
        // fallback: per-expert loop, stash H_e (1M floats) in the `final` region,
        // which is rewritten by smk_combine at the end.
        float* H = fin;
        for (int e = 0; e < E_NUM; ++e) {
            dim3 g1(N_TOK / BM, I_DIM / BN, 1);
            smk_ffn1<<<g1, 256, 0, stream>>>(x, W1, H, 1, e);
            dim3 g2(N_TOK / BM, C_DIM / BN, 1);
            smk_ffn2<<<g2, 256, 0, stream>>>(H, W2, scores, thr, eo, 1, e);
        }
    }

    smk_combine<<<(N_TOK * C_DIM / 4) / 256, 256, 0, stream>>>(eo, fin);
}

// Round 2
// 619.709 us; speedup vs baseline: 2.0906x; 2.0906x over previous
//
#include <hip/hip_runtime.h>
#include <hip/hip_bf16.h>
#include <math.h>
#include <stdint.h>

#define N_TOK 4096
#define C_DIM 1024
#define E_NUM 16
#define I_DIM 256

typedef unsigned short ushort_t;
typedef __attribute__((ext_vector_type(8))) short bf16x8;
typedef __attribute__((ext_vector_type(4))) float f32x4;

#define AS1 __attribute__((address_space(1)))
#define AS3 __attribute__((address_space(3)))

__device__ __forceinline__ void glds16(const void* g, void* l) {
    __builtin_amdgcn_global_load_lds((const AS1 uint32_t*)g, (AS3 uint32_t*)l, 16, 0, 0);
}

__device__ __forceinline__ ushort_t bf16_rne(float v) {
    uint32_t u = __float_as_uint(v);
    u = (u + 0x7FFFu + ((u >> 16) & 1u)) >> 16;
    return (ushort_t)u;
}
__device__ __forceinline__ float bf16_val(ushort_t h) {
    return __uint_as_float(((uint32_t)h) << 16);
}
__device__ __forceinline__ float gelu_exact(float v) {
    return 0.5f * v * (1.0f + erff(v * 0.70710678118654752f));
}

// ============================================================================
// split: fp32 [R][K] -> swizzled split-panel format.
// Layout: for k-panel p (32 k's), row r, 128B row = 8 units of 16B:
//   units 0..3 = hi bf16 (k%32 = u*8..u*8+7), units 4..7 = lo bf16,
//   unit index XOR-swizzled by (r&7).  dst byte = ((p*R + r)*8 + u')*16 + (k&7)*2
// ============================================================================
__global__ __launch_bounds__(256) void smk_split(
    const float* __restrict__ src, char* __restrict__ dst, int R, int kush)
{
    const int u  = blockIdx.x * 256 + threadIdx.x;   // global unit id (8 k's)
    const int ku = 1 << kush;                        // units per row = K/8
    const int r  = u >> kush;
    const int k8 = u & (ku - 1);
    const int p  = k8 >> 2;
    const int uh = (k8 & 3) ^ (r & 7);

    const float* s = src + ((size_t)r << (kush + 3)) + k8 * 8;
    float4 a = *(const float4*)(s);
    float4 b = *(const float4*)(s + 4);
    float f[8] = {a.x, a.y, a.z, a.w, b.x, b.y, b.z, b.w};

    uint4 hi4, lo4;
    ushort_t* hp = (ushort_t*)&hi4;
    ushort_t* lp = (ushort_t*)&lo4;
    #pragma unroll
    for (int j = 0; j < 8; ++j) {
        ushort_t h = bf16_rne(f[j]);
        hp[j] = h;
        lp[j] = bf16_rne(f[j] - bf16_val(h));
    }
    size_t ob = (((size_t)p * R + r) * 8 + uh) * 16;
    *(uint4*)(dst + ob)        = hi4;
    *(uint4*)(dst + (ob ^ 64)) = lo4;
}

// ============================================================================
// gate: 16 tokens per block, sim staged in LDS.
// ============================================================================
__global__ __launch_bounds__(256) void smk_gate2(
    const float* __restrict__ x, const float* __restrict__ sim,
    const float* __restrict__ thr,
    float* __restrict__ scores, float* __restrict__ kpt)
{
    __shared__ __align__(16) float ss[C_DIM * E_NUM];  // 64KB
    __shared__ float pm[16][17];
    __shared__ float inv_ns[E_NUM];
    __shared__ float mrow[16][17];

    const int tid = threadIdx.x;
    #pragma unroll
    for (int q = 0; q < 16; ++q)
        *(float4*)&ss[q * 1024 + tid * 4] = *(const float4*)&sim[q * 1024 + tid * 4];
    __syncthreads();

    const int e = tid & 15;
    const int g = tid >> 4;
    float ps = 0.f;
    for (int c = g; c < C_DIM; c += 16) {
        float v = ss[c * 16 + e];
        ps = fmaf(v, v, ps);
    }
    pm[g][e] = ps;
    __syncthreads();
    if (tid < 16) {
        float s = 0.f;
        #pragma unroll
        for (int gg = 0; gg < 16; ++gg) s += pm[gg][tid];
        inv_ns[tid] = 1.f / fmaxf(sqrtf(s), 1e-12f);
    }
    __syncthreads();

    const int t = blockIdx.x * 16 + g;
    const float* xr = x + (size_t)t * C_DIM;
    float dot = 0.f, sq = 0.f;
    for (int c = 0; c < C_DIM; c += 4) {
        float4 xv = *(const float4*)&xr[c];
        dot = fmaf(xv.x, ss[(c + 0) * 16 + e], dot);
        dot = fmaf(xv.y, ss[(c + 1) * 16 + e], dot);
        dot = fmaf(xv.z, ss[(c + 2) * 16 + e], dot);
        dot = fmaf(xv.w, ss[(c + 3) * 16 + e], dot);
        sq  = fmaf(xv.x, xv.x, sq); sq = fmaf(xv.y, xv.y, sq);
        sq  = fmaf(xv.z, xv.z, sq); sq = fmaf(xv.w, xv.w, sq);
    }
    float sc = dot * inv_ns[e] * (1.f / fmaxf(sqrtf(sq), 1e-12f));
    scores[(size_t)t * E_NUM + e] = sc;
    mrow[g][e] = (sc > thr[0]) ? 1.f : 0.f;
    __syncthreads();
    if (e == 0) {
        float k = 0.f;
        #pragma unroll
        for (int ee = 0; ee < 16; ++ee) k += mrow[g][ee];
        kpt[t] = k;
    }
}

// ============================================================================
// MFMA FFN1: H = gelu(X @ W1[e]^T), 3-product split-bf16.
// Grid (32, 2, 16), 256 thr. Tiles 128x128, BK=32.
// ============================================================================
__global__ __launch_bounds__(256) void smk_ffn1_mfma(
    const char* __restrict__ Xs, const char* __restrict__ W1s,
    char* __restrict__ Hs)
{
    __shared__ char As[16384];
    __shared__ char Bs[16384];

    const int e  = blockIdx.z;
    const int t0 = blockIdx.x * 128;
    const int i0 = blockIdx.y * 128;
    const int tid  = threadIdx.x;
    const int lane = tid & 63;
    const int w    = tid >> 6;
    const int wr   = w >> 1, wc = w & 1;

    f32x4 acc[4][4];
    #pragma unroll
    for (int mi = 0; mi < 4; ++mi)
        #pragma unroll
        for (int ni = 0; ni < 4; ++ni)
            acc[mi][ni] = (f32x4){0.f, 0.f, 0.f, 0.f};

    const char* Ag = Xs  + (size_t)t0 * 128 + tid * 16;
    const char* Bg = W1s + ((size_t)(e * 256) + i0) * 128 + tid * 16;

    for (int p = 0; p < 32; ++p) {
        __syncthreads();
        const char* ga = Ag + (size_t)p * (4096 * 128);
        const char* gb = Bg + (size_t)p * (4096 * 128);
        #pragma unroll
        for (int q = 0; q < 4; ++q) {
            glds16(ga + q * 4096, As + q * 4096 + tid * 16);
            glds16(gb + q * 4096, Bs + q * 4096 + tid * 16);
        }
        __syncthreads();

        bf16x8 ah[4], al[4], bh[4], bl[4];
        #pragma unroll
        for (int mi = 0; mi < 4; ++mi) {
            int r   = wr * 64 + mi * 16 + (lane & 15);
            int ubh = (((lane >> 4)    ) ^ (r & 7)) * 16;
            int ubl = (((lane >> 4) | 4) ^ (r & 7)) * 16;
            ah[mi] = *(const bf16x8*)(As + r * 128 + ubh);
            al[mi] = *(const bf16x8*)(As + r * 128 + ubl);
        }
        #pragma unroll
        for (int ni = 0; ni < 4; ++ni) {
            int r   = wc * 64 + ni * 16 + (lane & 15);
            int ubh = (((lane >> 4)    ) ^ (r & 7)) * 16;
            int ubl = (((lane >> 4) | 4) ^ (r & 7)) * 16;
            bh[ni] = *(const bf16x8*)(Bs + r * 128 + ubh);
            bl[ni] = *(const bf16x8*)(Bs + r * 128 + ubl);
        }
        #pragma unroll
        for (int mi = 0; mi < 4; ++mi)
            #pragma unroll
            for (int ni = 0; ni < 4; ++ni) {
                acc[mi][ni] = __builtin_amdgcn_mfma_f32_16x16x32_bf16(ah[mi], bh[ni], acc[mi][ni], 0, 0, 0);
                acc[mi][ni] = __builtin_amdgcn_mfma_f32_16x16x32_bf16(al[mi], bh[ni], acc[mi][ni], 0, 0, 0);
                acc[mi][ni] = __builtin_amdgcn_mfma_f32_16x16x32_bf16(ah[mi], bl[ni], acc[mi][ni], 0, 0, 0);
            }
    }

    // epilogue: gelu, split to hi/lo bf16, write swizzled Hs[e][p][t][u']
    const int rb = (lane >> 4) * 4;
    #pragma unroll
    for (int mi = 0; mi < 4; ++mi)
        #pragma unroll
        for (int ni = 0; ni < 4; ++ni) {
            int ig = i0 + wc * 64 + ni * 16 + (lane & 15);
            int pp = ig >> 5, kk = ig & 31;
            #pragma unroll
            for (int j = 0; j < 4; ++j) {
                int t = t0 + wr * 64 + mi * 16 + rb + j;
                float v = gelu_exact(acc[mi][ni][j]);
                ushort_t h = bf16_rne(v);
                ushort_t l = bf16_rne(v - bf16_val(h));
                size_t ob = ((size_t)((e * 8 + pp) * 4096 + t)) * 128
                          + (((kk >> 3) ^ (t & 7)) * 16) + (kk & 7) * 2;
                *(ushort_t*)(Hs + ob)        = h;
                *(ushort_t*)(Hs + (ob ^ 64)) = l;
            }
        }
}

// ============================================================================
// MFMA FFN2: eo[:,e,:] = mask * (H[e] @ W2[e]^T). Grid (32, 8, 16).
// ============================================================================
__global__ __launch_bounds__(256) void smk_ffn2_mfma(
    const char* __restrict__ Hs, const char* __restrict__ W2s,
    const float* __restrict__ scores, const float* __restrict__ thr,
    float* __restrict__ eo)
{
    __shared__ char As[16384];
    __shared__ char Bs[16384];

    const int e  = blockIdx.z;
    const int t0 = blockIdx.x * 128;
    const int c0 = blockIdx.y * 128;
    const int tid  = threadIdx.x;
    const int lane = tid & 63;
    const int w    = tid >> 6;
    const int wr   = w >> 1, wc = w & 1;

    f32x4 acc[4][4];
    #pragma unroll
    for (int mi = 0; mi < 4; ++mi)
        #pragma unroll
        for (int ni = 0; ni < 4; ++ni)
            acc[mi][ni] = (f32x4){0.f, 0.f, 0.f, 0.f};

    const char* Ag = Hs  + ((size_t)(e * 8) * 4096 + t0) * 128 + tid * 16;
    const char* Bg = W2s + ((size_t)(e * 1024) + c0) * 128 + tid * 16;

    for (int p = 0; p < 8; ++p) {
        __syncthreads();
        const char* ga = Ag + (size_t)p * (4096 * 128);
        const char* gb = Bg + (size_t)p * (16384 * 128);
        #pragma unroll
        for (int q = 0; q < 4; ++q) {
            glds16(ga + q * 4096, As + q * 4096 + tid * 16);
            glds16(gb + q * 4096, Bs + q * 4096 + tid * 16);
        }
        __syncthreads();

        bf16x8 ah[4], al[4], bh[4], bl[4];
        #pragma unroll
        for (int mi = 0; mi < 4; ++mi) {
            int r   = wr * 64 + mi * 16 + (lane & 15);
            int ubh = (((lane >> 4)    ) ^ (r & 7)) * 16;
            int ubl = (((lane >> 4) | 4) ^ (r & 7)) * 16;
            ah[mi] = *(const bf16x8*)(As + r * 128 + ubh);
            al[mi] = *(const bf16x8*)(As + r * 128 + ubl);
        }
        #pragma unroll
        for (int ni = 0; ni < 4; ++ni) {
            int r   = wc * 64 + ni * 16 + (lane & 15);
            int ubh = (((lane >> 4)    ) ^ (r & 7)) * 16;
            int ubl = (((lane >> 4) | 4) ^ (r & 7)) * 16;
            bh[ni] = *(const bf16x8*)(Bs + r * 128 + ubh);
            bl[ni] = *(const bf16x8*)(Bs + r * 128 + ubl);
        }
        #pragma unroll
        for (int mi = 0; mi < 4; ++mi)
            #pragma unroll
            for (int ni = 0; ni < 4; ++ni) {
                acc[mi][ni] = __builtin_amdgcn_mfma_f32_16x16x32_bf16(ah[mi], bh[ni], acc[mi][ni], 0, 0, 0);
                acc[mi][ni] = __builtin_amdgcn_mfma_f32_16x16x32_bf16(al[mi], bh[ni], acc[mi][ni], 0, 0, 0);
                acc[mi][ni] = __builtin_amdgcn_mfma_f32_16x16x32_bf16(ah[mi], bl[ni], acc[mi][ni], 0, 0, 0);
            }
    }

    const float th = thr[0];
    const int rb = (lane >> 4) * 4;
    float msk[4][4];
    #pragma unroll
    for (int mi = 0; mi < 4; ++mi)
        #pragma unroll
        for (int j = 0; j < 4; ++j) {
            int t = t0 + wr * 64 + mi * 16 + rb + j;
            msk[mi][j] = (scores[(size_t)t * E_NUM + e] > th) ? 1.f : 0.f;
        }
    #pragma unroll
    for (int mi = 0; mi < 4; ++mi)
        #pragma unroll
        for (int ni = 0; ni < 4; ++ni) {
            int c = c0 + wc * 64 + ni * 16 + (lane & 15);
            #pragma unroll
            for (int j = 0; j < 4; ++j) {
                int t = t0 + wr * 64 + mi * 16 + rb + j;
                eo[((size_t)t * E_NUM + e) * C_DIM + c] = acc[mi][ni][j] * msk[mi][j];
            }
        }
}

// ============================================================================
// combine: final = sum_e eo
// ============================================================================
__global__ __launch_bounds__(256) void smk_combine(
    const float* __restrict__ eo, float* __restrict__ fin)
{
    size_t idx = ((size_t)blockIdx.x * 256 + threadIdx.x) * 4;
    size_t t = idx / C_DIM;
    int c = (int)(idx % C_DIM);
    const float* p = eo + (size_t)t * E_NUM * C_DIM + c;
    float4 s = {0.f, 0.f, 0.f, 0.f};
    #pragma unroll
    for (int e = 0; e < E_NUM; ++e) {
        float4 v = *(const float4*)&p[(size_t)e * C_DIM];
        s.x += v.x; s.y += v.y; s.z += v.z; s.w += v.w;
    }
    *(float4*)&fin[idx] = s;
}

// ============================================================================
// fp32 fallback path (round-1 kernels) — used only if ws too small
// ============================================================================
#define BM 64
#define BN 64
#define KC 16
#define LDP 68

__global__ __launch_bounds__(256) void smk_ffn1(
    const float* __restrict__ X, const float* __restrict__ W1,
    float* __restrict__ H, int eh, int ez0)
{
    const int e  = blockIdx.z + ez0;
    const int t0 = blockIdx.x * BM;
    const int i0 = blockIdx.y * BN;
    const float* Ap = X + (size_t)t0 * C_DIM;
    const float* Bp = W1 + ((size_t)e * I_DIM + i0) * C_DIM;
    __shared__ __align__(16) float As[KC][LDP];
    __shared__ __align__(16) float Bs[KC][LDP];
    const int tid = threadIdx.x;
    const int tx = tid & 15, ty = tid >> 4;
    const int lm = tid >> 2;
    const int lk = (tid & 3) * 4;
    float acc[4][4] = {};
    for (int k0 = 0; k0 < C_DIM; k0 += KC) {
        float4 av = *(const float4*)&Ap[(size_t)lm * C_DIM + k0 + lk];
        float4 bv = *(const float4*)&Bp[(size_t)lm * C_DIM + k0 + lk];
        __syncthreads();
        As[lk + 0][lm] = av.x; As[lk + 1][lm] = av.y;
        As[lk + 2][lm] = av.z; As[lk + 3][lm] = av.w;
        Bs[lk + 0][lm] = bv.x; Bs[lk + 1][lm] = bv.y;
        Bs[lk + 2][lm] = bv.z; Bs[lk + 3][lm] = bv.w;
        __syncthreads();
        #pragma unroll
        for (int k = 0; k < KC; ++k) {
            float4 a4 = *(const float4*)&As[k][ty * 4];
            float4 b4 = *(const float4*)&Bs[k][tx * 4];
            float a[4] = {a4.x, a4.y, a4.z, a4.w};
            float b[4] = {b4.x, b4.y, b4.z, b4.w};
            #pragma unroll
            for (int i = 0; i < 4; ++i)
                #pragma unroll
                for (int j = 0; j < 4; ++j)
                    acc[i][j] = fmaf(a[i], b[j], acc[i][j]);
        }
    }
    const size_t hrow = (size_t)eh * I_DIM;
    float* Hp = H + ((eh == E_NUM) ? (size_t)e * I_DIM : 0);
    #pragma unroll
    for (int i = 0; i < 4; ++i) {
        int t = t0 + ty * 4 + i;
        float4 o;
        o.x = gelu_exact(acc[i][0]); o.y = gelu_exact(acc[i][1]);
        o.z = gelu_exact(acc[i][2]); o.w = gelu_exact(acc[i][3]);
        *(float4*)&Hp[(size_t)t * hrow + i0 + tx * 4] = o;
    }
}

__global__ __launch_bounds__(256) void smk_ffn2(
    const float* __restrict__ Hst, const float* __restrict__ W2,
    const float* __restrict__ scores, const float* __restrict__ thr,
    float* __restrict__ eo, int eh, int ez0)
{
    const int e  = blockIdx.z + ez0;
    const int t0 = blockIdx.x * BM;
    const int c0 = blockIdx.y * BN;
    const size_t hrow = (size_t)eh * I_DIM;
    const float* Ap = Hst + ((eh == E_NUM) ? (size_t)e * I_DIM : 0) + (size_t)t0 * hrow;
    const float* Bp = W2 + ((size_t)e * C_DIM + c0) * I_DIM;
    __shared__ __align__(16) float As[KC][LDP];
    __shared__ __align__(16) float Bs[KC][LDP];
    const int tid = threadIdx.x;
    const int tx = tid & 15, ty = tid >> 4;
    const int lm = tid >> 2;
    const int lk = (tid & 3) * 4;
    float acc[4][4] = {};
    for (int k0 = 0; k0 < I_DIM; k0 += KC) {
        float4 av = *(const float4*)&Ap[(size_t)lm * hrow + k0 + lk];
        float4 bv = *(const float4*)&Bp[(size_t)lm * I_DIM + k0 + lk];
        __syncthreads();
        As[lk + 0][lm] = av.x; As[lk + 1][lm] = av.y;
        As[lk + 2][lm] = av.z; As[lk + 3][lm] = av.w;
        Bs[lk + 0][lm] = bv.x; Bs[lk + 1][lm] = bv.y;
        Bs[lk + 2][lm] = bv.z; Bs[lk + 3][lm] = bv.w;
        __syncthreads();
        #pragma unroll
        for (int k = 0; k < KC; ++k) {
            float4 a4 = *(const float4*)&As[k][ty * 4];
            float4 b4 = *(const float4*)&Bs[k][tx * 4];
            float a[4] = {a4.x, a4.y, a4.z, a4.w};
            float b[4] = {b4.x, b4.y, b4.z, b4.w};
            #pragma unroll
            for (int i = 0; i < 4; ++i)
                #pragma unroll
                for (int j = 0; j < 4; ++j)
                    acc[i][j] = fmaf(a[i], b[j], acc[i][j]);
        }
    }
    const float th = thr[0];
    #pragma unroll
    for (int i = 0; i < 4; ++i) {
        int t = t0 + ty * 4 + i;
        float m = (scores[(size_t)t * E_NUM + e] > th) ? 1.f : 0.f;
        float4 o;
        o.x = acc[i][0] * m; o.y = acc[i][1] * m;
        o.z = acc[i][2] * m; o.w = acc[i][3] * m;
        *(float4*)&eo[((size_t)t * E_NUM + e) * C_DIM + c0 + tx * 4] = o;
    }
}

// ============================================================================
extern "C" void kernel_launch(void* const* d_in, const int* in_sizes, int n_in,
                              void* d_out, int out_size, void* d_ws, size_t ws_size,
                              hipStream_t stream) {
    const float* x   = (const float*)d_in[0];
    const float* sim = (const float*)d_in[1];
    const float* thr = (const float*)d_in[2];
    const float* W1  = (const float*)d_in[3];
    const float* W2  = (const float*)d_in[4];

    float* out    = (float*)d_out;
    float* fin    = out;
    float* scores = out + (size_t)N_TOK * C_DIM;
    float* eo     = scores + (size_t)N_TOK * E_NUM;
    float* kpt    = eo + (size_t)N_TOK * E_NUM * C_DIM;

    smk_gate2<<<N_TOK / 16, 256, 0, stream>>>(x, sim, thr, scores, kpt);

    const size_t SZ_XS  = 16777216;  // 32p x 4096 x 128B
    const size_t SZ_W1S = 16777216;  // 32p x 4096 x 128B
    const size_t SZ_W2S = 16777216;  // 8p x 16384 x 128B
    const size_t SZ_HS  = 67108864;  // 16e x 8p x 4096 x 128B
    const size_t WS_NEED = SZ_XS + SZ_W1S + SZ_W2S + SZ_HS;  // 117,440,512

    if (ws_size >= WS_NEED) {
        char* Xs  = (char*)d_ws;
        char* W1s = Xs + SZ_XS;
        char* W2s = W1s + SZ_W1S;
        char* Hs  = W2s + SZ_W2S;

        smk_split<<<2048, 256, 0, stream>>>(x,  Xs,  4096,  7);
        smk_split<<<2048, 256, 0, stream>>>(W1, W1s, 4096,  7);
        smk_split<<<2048, 256, 0, stream>>>(W2, W2s, 16384, 5);

        dim3 g1(32, 2, 16);
        smk_ffn1_mfma<<<g1, 256, 0, stream>>>(Xs, W1s, Hs);
        dim3 g2(32, 8, 16);
        smk_ffn2_mfma<<<g2, 256, 0, stream>>>(Hs, W2s, scores, thr, eo);
    } else {
        // fp32 fallback
        const size_t needH = (size_t)N_TOK * E_NUM * I_DIM * sizeof(float);
        if (ws_size >= needH) {
            float* H = (float*)d_ws;
            dim3 g1(N_TOK / BM, I_DIM / BN, E_NUM);
            smk_ffn1<<<g1, 256, 0, stream>>>(x, W1, H, E_NUM, 0);
            dim3 g2(N_TOK / BM, C_DIM / BN, E_NUM);
            smk_ffn2<<<g2, 256, 0, stream>>>(H, W2, scores, thr, eo, E_NUM, 0);
        } else {
            float* H = fin;
            for (int e = 0; e < E_NUM; ++e) {
                dim3 g1(N_TOK / BM, I_DIM / BN, 1);
                smk_ffn1<<<g1, 256, 0, stream>>>(x, W1, H, 1, e);
                dim3 g2(N_TOK / BM, C_DIM / BN, 1);
                smk_ffn2<<<g2, 256, 0, stream>>>(H, W2, scores, thr, eo, 1, e);
            }
        }
    }

    smk_combine<<<(N_TOK * C_DIM / 4) / 256, 256, 0, stream>>>(eo, fin);
}

// Round 6
// 527.392 us; speedup vs baseline: 2.4566x; 1.1750x over previous
//
#include <hip/hip_runtime.h>
#include <hip/hip_bf16.h>
#include <math.h>
#include <stdint.h>

#define N_TOK 4096
#define C_DIM 1024
#define E_NUM 16
#define I_DIM 256

typedef unsigned short ushort_t;
typedef __attribute__((ext_vector_type(8))) short bf16x8;
typedef __attribute__((ext_vector_type(4))) float f32x4;

#define AS1 __attribute__((address_space(1)))
#define AS3 __attribute__((address_space(3)))

__device__ __forceinline__ void glds16(const void* g, void* l) {
    __builtin_amdgcn_global_load_lds((const AS1 uint32_t*)g, (AS3 uint32_t*)l, 16, 0, 0);
}

__device__ __forceinline__ ushort_t bf16_rne(float v) {
    uint32_t u = __float_as_uint(v);
    u = (u + 0x7FFFu + ((u >> 16) & 1u)) >> 16;
    return (ushort_t)u;
}
__device__ __forceinline__ float bf16_val(ushort_t h) {
    return __uint_as_float(((uint32_t)h) << 16);
}
__device__ __forceinline__ float gelu_exact(float v) {
    return 0.5f * v * (1.0f + erff(v * 0.70710678118654752f));
}

// ============================================================================
// smk_split: fp32 [R][K] -> hi+lo split-panel format (A-side / W2-B-side).
// k-panel p = 32 k's; row = 128B = 8 units of 16B; units 0..3 hi, 4..7 lo;
// unit XOR-swizzled by (r&7).  byte = ((p*R + r)*8 + u')*16 + (k&7)*2
// ============================================================================
__global__ __launch_bounds__(256) void smk_split(
    const float* __restrict__ src, char* __restrict__ dst, int R, int kush)
{
    const int u  = blockIdx.x * 256 + threadIdx.x;
    const int ku = 1 << kush;
    const int r  = u >> kush;
    const int k8 = u & (ku - 1);
    const int p  = k8 >> 2;
    const int uh = (k8 & 3) ^ (r & 7);

    const float* s = src + ((size_t)r << (kush + 3)) + k8 * 8;
    float4 a = *(const float4*)(s);
    float4 b = *(const float4*)(s + 4);
    float f[8] = {a.x, a.y, a.z, a.w, b.x, b.y, b.z, b.w};

    uint4 hi4, lo4;
    ushort_t* hp = (ushort_t*)&hi4;
    ushort_t* lp = (ushort_t*)&lo4;
    #pragma unroll
    for (int j = 0; j < 8; ++j) {
        ushort_t h = bf16_rne(f[j]);
        hp[j] = h;
        lp[j] = bf16_rne(f[j] - bf16_val(h));
    }
    size_t ob = (((size_t)p * R + r) * 8 + uh) * 16;
    *(uint4*)(dst + ob)        = hi4;
    *(uint4*)(dst + (ob ^ 64)) = lo4;
}

// ============================================================================
// smk_splitBH: fp32 [R][K] -> hi-only DUAL-PANEL format (W1 B-side).
// Row-group q covers panels 2q,2q+1; row = 128B = 8 units; unit
// u = ((k>>3)&3) | ((p&1)<<2), swizzled ^(r&7).
// ============================================================================
__global__ __launch_bounds__(256) void smk_splitBH(
    const float* __restrict__ src, char* __restrict__ dst, int R, int kush)
{
    const int u  = blockIdx.x * 256 + threadIdx.x;
    const int ku = 1 << kush;
    const int r  = u >> kush;
    const int k8 = u & (ku - 1);
    const int p  = k8 >> 2;
    const int q  = p >> 1;
    const int uh = ((k8 & 3) | ((p & 1) << 2)) ^ (r & 7);

    const float* s = src + ((size_t)r << (kush + 3)) + k8 * 8;
    float4 a = *(const float4*)(s);
    float4 b = *(const float4*)(s + 4);
    float f[8] = {a.x, a.y, a.z, a.w, b.x, b.y, b.z, b.w};

    uint4 hi4;
    ushort_t* hp = (ushort_t*)&hi4;
    #pragma unroll
    for (int j = 0; j < 8; ++j) hp[j] = bf16_rne(f[j]);

    *(uint4*)(dst + (((size_t)q * R + r) * 8 + uh) * 16) = hi4;
}

// ============================================================================
// gate: 16 tokens per block, sim staged in LDS.
// ============================================================================
__global__ __launch_bounds__(256) void smk_gate2(
    const float* __restrict__ x, const float* __restrict__ sim,
    const float* __restrict__ thr,
    float* __restrict__ scores, float* __restrict__ kpt)
{
    __shared__ __align__(16) float ss[C_DIM * E_NUM];
    __shared__ float pm[16][17];
    __shared__ float inv_ns[E_NUM];
    __shared__ float mrow[16][17];

    const int tid = threadIdx.x;
    #pragma unroll
    for (int q = 0; q < 16; ++q)
        *(float4*)&ss[q * 1024 + tid * 4] = *(const float4*)&sim[q * 1024 + tid * 4];
    __syncthreads();

    const int e = tid & 15;
    const int g = tid >> 4;
    float ps = 0.f;
    for (int c = g; c < C_DIM; c += 16) {
        float v = ss[c * 16 + e];
        ps = fmaf(v, v, ps);
    }
    pm[g][e] = ps;
    __syncthreads();
    if (tid < 16) {
        float s = 0.f;
        #pragma unroll
        for (int gg = 0; gg < 16; ++gg) s += pm[gg][tid];
        inv_ns[tid] = 1.f / fmaxf(sqrtf(s), 1e-12f);
    }
    __syncthreads();

    const int t = blockIdx.x * 16 + g;
    const float* xr = x + (size_t)t * C_DIM;
    float dot = 0.f, sq = 0.f;
    for (int c = 0; c < C_DIM; c += 4) {
        float4 xv = *(const float4*)&xr[c];
        dot = fmaf(xv.x, ss[(c + 0) * 16 + e], dot);
        dot = fmaf(xv.y, ss[(c + 1) * 16 + e], dot);
        dot = fmaf(xv.z, ss[(c + 2) * 16 + e], dot);
        dot = fmaf(xv.w, ss[(c + 3) * 16 + e], dot);
        sq  = fmaf(xv.x, xv.x, sq); sq = fmaf(xv.y, xv.y, sq);
        sq  = fmaf(xv.z, xv.z, sq); sq = fmaf(xv.w, xv.w, sq);
    }
    float sc = dot * inv_ns[e] * (1.f / fmaxf(sqrtf(sq), 1e-12f));
    scores[(size_t)t * E_NUM + e] = sc;
    mrow[g][e] = (sc > thr[0]) ? 1.f : 0.f;
    __syncthreads();
    if (e == 0) {
        float k = 0.f;
        #pragma unroll
        for (int ee = 0; ee < 16; ++ee) k += mrow[g][ee];
        kpt[t] = k;
    }
}

// ============================================================================
// FFN1: H = gelu(X @ W1[e]^T); A = X hi+lo (exact), B = W1 hi only.
// 2 MFMA / fragment / K-step. Grid (32, 2, 16), 256 thr, 128x128 tiles, BK=32.
// H written hi-only dual-panel.
// ============================================================================
__global__ __launch_bounds__(256) void smk_ffn1_mfma(
    const char* __restrict__ Xs, const char* __restrict__ W1h,
    char* __restrict__ Hsh)
{
    __shared__ char As[16384];
    __shared__ char Bs[16384];   // dual-panel: panels {p, p+1} hi

    const int e  = blockIdx.z;
    const int t0 = blockIdx.x * 128;
    const int i0 = blockIdx.y * 128;
    const int tid  = threadIdx.x;
    const int lane = tid & 63;
    const int w    = tid >> 6;
    const int wr   = w >> 1, wc = w & 1;

    f32x4 acc[4][4];
    #pragma unroll
    for (int mi = 0; mi < 4; ++mi)
        #pragma unroll
        for (int ni = 0; ni < 4; ++ni)
            acc[mi][ni] = (f32x4){0.f, 0.f, 0.f, 0.f};

    const char* Ag = Xs  + (size_t)t0 * 128 + tid * 16;
    const char* Bg = W1h + ((size_t)(e * 256) + i0) * 128 + tid * 16;

    for (int p = 0; p < 32; ++p) {
        __syncthreads();
        const char* ga = Ag + (size_t)p * (4096 * 128);
        #pragma unroll
        for (int q = 0; q < 4; ++q)
            glds16(ga + q * 4096, As + q * 4096 + tid * 16);
        if ((p & 1) == 0) {
            const char* gb = Bg + (size_t)(p >> 1) * (4096 * 128);
            #pragma unroll
            for (int q = 0; q < 4; ++q)
                glds16(gb + q * 4096, Bs + q * 4096 + tid * 16);
        }
        __syncthreads();

        bf16x8 ah[4], al[4], bh[4];
        #pragma unroll
        for (int mi = 0; mi < 4; ++mi) {
            int r   = wr * 64 + mi * 16 + (lane & 15);
            int ubh = (((lane >> 4)    ) ^ (r & 7)) * 16;
            int ubl = (((lane >> 4) | 4) ^ (r & 7)) * 16;
            ah[mi] = *(const bf16x8*)(As + r * 128 + ubh);
            al[mi] = *(const bf16x8*)(As + r * 128 + ubl);
        }
        const int ubsel = (lane >> 4) | ((p & 1) << 2);
        #pragma unroll
        for (int ni = 0; ni < 4; ++ni) {
            int r  = wc * 64 + ni * 16 + (lane & 15);
            int ub = (ubsel ^ (r & 7)) * 16;
            bh[ni] = *(const bf16x8*)(Bs + r * 128 + ub);
        }
        #pragma unroll
        for (int mi = 0; mi < 4; ++mi)
            #pragma unroll
            for (int ni = 0; ni < 4; ++ni) {
                acc[mi][ni] = __builtin_amdgcn_mfma_f32_16x16x32_bf16(ah[mi], bh[ni], acc[mi][ni], 0, 0, 0);
                acc[mi][ni] = __builtin_amdgcn_mfma_f32_16x16x32_bf16(al[mi], bh[ni], acc[mi][ni], 0, 0, 0);
            }
    }

    // epilogue: gelu, round to bf16 hi, write dual-panel Hsh[e][q][t][u']
    const int rb = (lane >> 4) * 4;
    #pragma unroll
    for (int mi = 0; mi < 4; ++mi)
        #pragma unroll
        for (int ni = 0; ni < 4; ++ni) {
            int ig = i0 + wc * 64 + ni * 16 + (lane & 15);
            int pp = ig >> 5, qq = pp >> 1;
            int uu = ((ig >> 3) & 3) | ((pp & 1) << 2);
            #pragma unroll
            for (int j = 0; j < 4; ++j) {
                int t = t0 + wr * 64 + mi * 16 + rb + j;
                float v = gelu_exact(acc[mi][ni][j]);
                size_t ob = (((size_t)((e * 4 + qq) * 4096 + t)) * 8 + (uu ^ (t & 7))) * 16
                          + (ig & 7) * 2;
                *(ushort_t*)(Hsh + ob) = bf16_rne(v);
            }
        }
}

// ============================================================================
// FFN2: eo[:,e,:] = mask * (H[e] @ W2[e]^T); A = H hi only, B = W2 hi+lo.
// Grid (32, 8, 16).
// ============================================================================
__global__ __launch_bounds__(256) void smk_ffn2_mfma(
    const char* __restrict__ Hsh, const char* __restrict__ W2s,
    const float* __restrict__ scores, const float* __restrict__ thr,
    float* __restrict__ eo)
{
    __shared__ char As[16384];   // dual-panel: panels {p, p+1} hi
    __shared__ char Bs[16384];

    const int e  = blockIdx.z;
    const int t0 = blockIdx.x * 128;
    const int c0 = blockIdx.y * 128;
    const int tid  = threadIdx.x;
    const int lane = tid & 63;
    const int w    = tid >> 6;
    const int wr   = w >> 1, wc = w & 1;

    f32x4 acc[4][4];
    #pragma unroll
    for (int mi = 0; mi < 4; ++mi)
        #pragma unroll
        for (int ni = 0; ni < 4; ++ni)
            acc[mi][ni] = (f32x4){0.f, 0.f, 0.f, 0.f};

    const char* Ag = Hsh + ((size_t)(e * 4) * 4096 + t0) * 128 + tid * 16;
    const char* Bg = W2s + ((size_t)(e * 1024) + c0) * 128 + tid * 16;

    for (int p = 0; p < 8; ++p) {
        __syncthreads();
        if ((p & 1) == 0) {
            const char* ga = Ag + (size_t)(p >> 1) * (4096 * 128);
            #pragma unroll
            for (int q = 0; q < 4; ++q)
                glds16(ga + q * 4096, As + q * 4096 + tid * 16);
        }
        const char* gb = Bg + (size_t)p * (16384 * 128);
        #pragma unroll
        for (int q = 0; q < 4; ++q)
            glds16(gb + q * 4096, Bs + q * 4096 + tid * 16);
        __syncthreads();

        bf16x8 ah[4], bh[4], bl[4];
        const int uasel = (lane >> 4) | ((p & 1) << 2);
        #pragma unroll
        for (int mi = 0; mi < 4; ++mi) {
            int r  = wr * 64 + mi * 16 + (lane & 15);
            int ua = (uasel ^ (r & 7)) * 16;
            ah[mi] = *(const bf16x8*)(As + r * 128 + ua);
        }
        #pragma unroll
        for (int ni = 0; ni < 4; ++ni) {
            int r   = wc * 64 + ni * 16 + (lane & 15);
            int ubh = (((lane >> 4)    ) ^ (r & 7)) * 16;
            int ubl = (((lane >> 4) | 4) ^ (r & 7)) * 16;
            bh[ni] = *(const bf16x8*)(Bs + r * 128 + ubh);
            bl[ni] = *(const bf16x8*)(Bs + r * 128 + ubl);
        }
        #pragma unroll
        for (int mi = 0; mi < 4; ++mi)
            #pragma unroll
            for (int ni = 0; ni < 4; ++ni) {
                acc[mi][ni] = __builtin_amdgcn_mfma_f32_16x16x32_bf16(ah[mi], bh[ni], acc[mi][ni], 0, 0, 0);
                acc[mi][ni] = __builtin_amdgcn_mfma_f32_16x16x32_bf16(ah[mi], bl[ni], acc[mi][ni], 0, 0, 0);
            }
    }

    const float th = thr[0];
    const int rb = (lane >> 4) * 4;
    float msk[4][4];
    #pragma unroll
    for (int mi = 0; mi < 4; ++mi)
        #pragma unroll
        for (int j = 0; j < 4; ++j) {
            int t = t0 + wr * 64 + mi * 16 + rb + j;
            msk[mi][j] = (scores[(size_t)t * E_NUM + e] > th) ? 1.f : 0.f;
        }
    #pragma unroll
    for (int mi = 0; mi < 4; ++mi)
        #pragma unroll
        for (int ni = 0; ni < 4; ++ni) {
            int c = c0 + wc * 64 + ni * 16 + (lane & 15);
            #pragma unroll
            for (int j = 0; j < 4; ++j) {
                int t = t0 + wr * 64 + mi * 16 + rb + j;
                eo[((size_t)t * E_NUM + e) * C_DIM + c] = acc[mi][ni][j] * msk[mi][j];
            }
        }
}

// ============================================================================
// combine: final = sum_e eo
// ============================================================================
__global__ __launch_bounds__(256) void smk_combine(
    const float* __restrict__ eo, float* __restrict__ fin)
{
    size_t idx = ((size_t)blockIdx.x * 256 + threadIdx.x) * 4;
    size_t t = idx / C_DIM;
    int c = (int)(idx % C_DIM);
    const float* p = eo + (size_t)t * E_NUM * C_DIM + c;
    float4 s = {0.f, 0.f, 0.f, 0.f};
    #pragma unroll
    for (int e = 0; e < E_NUM; ++e) {
        float4 v = *(const float4*)&p[(size_t)e * C_DIM];
        s.x += v.x; s.y += v.y; s.z += v.z; s.w += v.w;
    }
    *(float4*)&fin[idx] = s;
}

// ============================================================================
// fp32 fallback path — used only if ws too small
// ============================================================================
#define BM 64
#define BN 64
#define KC 16
#define LDP 68

__global__ __launch_bounds__(256) void smk_ffn1(
    const float* __restrict__ X, const float* __restrict__ W1,
    float* __restrict__ H, int eh, int ez0)
{
    const int e  = blockIdx.z + ez0;
    const int t0 = blockIdx.x * BM;
    const int i0 = blockIdx.y * BN;
    const float* Ap = X + (size_t)t0 * C_DIM;
    const float* Bp = W1 + ((size_t)e * I_DIM + i0) * C_DIM;
    __shared__ __align__(16) float As[KC][LDP];
    __shared__ __align__(16) float Bs[KC][LDP];
    const int tid = threadIdx.x;
    const int tx = tid & 15, ty = tid >> 4;
    const int lm = tid >> 2;
    const int lk = (tid & 3) * 4;
    float acc[4][4] = {};
    for (int k0 = 0; k0 < C_DIM; k0 += KC) {
        float4 av = *(const float4*)&Ap[(size_t)lm * C_DIM + k0 + lk];
        float4 bv = *(const float4*)&Bp[(size_t)lm * C_DIM + k0 + lk];
        __syncthreads();
        As[lk + 0][lm] = av.x; As[lk + 1][lm] = av.y;
        As[lk + 2][lm] = av.z; As[lk + 3][lm] = av.w;
        Bs[lk + 0][lm] = bv.x; Bs[lk + 1][lm] = bv.y;
        Bs[lk + 2][lm] = bv.z; Bs[lk + 3][lm] = bv.w;
        __syncthreads();
        #pragma unroll
        for (int k = 0; k < KC; ++k) {
            float4 a4 = *(const float4*)&As[k][ty * 4];
            float4 b4 = *(const float4*)&Bs[k][tx * 4];
            float a[4] = {a4.x, a4.y, a4.z, a4.w};
            float b[4] = {b4.x, b4.y, b4.z, b4.w};
            #pragma unroll
            for (int i = 0; i < 4; ++i)
                #pragma unroll
                for (int j = 0; j < 4; ++j)
                    acc[i][j] = fmaf(a[i], b[j], acc[i][j]);
        }
    }
    const size_t hrow = (size_t)eh * I_DIM;
    float* Hp = H + ((eh == E_NUM) ? (size_t)e * I_DIM : 0);
    #pragma unroll
    for (int i = 0; i < 4; ++i) {
        int t = t0 + ty * 4 + i;
        float4 o;
        o.x = gelu_exact(acc[i][0]); o.y = gelu_exact(acc[i][1]);
        o.z = gelu_exact(acc[i][2]); o.w = gelu_exact(acc[i][3]);
        *(float4*)&Hp[(size_t)t * hrow + i0 + tx * 4] = o;
    }
}

__global__ __launch_bounds__(256) void smk_ffn2(
    const float* __restrict__ Hst, const float* __restrict__ W2,
    const float* __restrict__ scores, const float* __restrict__ thr,
    float* __restrict__ eo, int eh, int ez0)
{
    const int e  = blockIdx.z + ez0;
    const int t0 = blockIdx.x * BM;
    const int c0 = blockIdx.y * BN;
    const size_t hrow = (size_t)eh * I_DIM;
    const float* Ap = Hst + ((eh == E_NUM) ? (size_t)e * I_DIM : 0) + (size_t)t0 * hrow;
    const float* Bp = W2 + ((size_t)e * C_DIM + c0) * I_DIM;
    __shared__ __align__(16) float As[KC][LDP];
    __shared__ __align__(16) float Bs[KC][LDP];
    const int tid = threadIdx.x;
    const int tx = tid & 15, ty = tid >> 4;
    const int lm = tid >> 2;
    const int lk = (tid & 3) * 4;
    float acc[4][4] = {};
    for (int k0 = 0; k0 < I_DIM; k0 += KC) {
        float4 av = *(const float4*)&Ap[(size_t)lm * hrow + k0 + lk];
        float4 bv = *(const float4*)&Bp[(size_t)lm * I_DIM + k0 + lk];
        __syncthreads();
        As[lk + 0][lm] = av.x; As[lk + 1][lm] = av.y;
        As[lk + 2][lm] = av.z; As[lk + 3][lm] = av.w;
        Bs[lk + 0][lm] = bv.x; Bs[lk + 1][lm] = bv.y;
        Bs[lk + 2][lm] = bv.z; Bs[lk + 3][lm] = bv.w;
        __syncthreads();
        #pragma unroll
        for (int k = 0; k < KC; ++k) {
            float4 a4 = *(const float4*)&As[k][ty * 4];
            float4 b4 = *(const float4*)&Bs[k][tx * 4];
            float a[4] = {a4.x, a4.y, a4.z, a4.w};
            float b[4] = {b4.x, b4.y, b4.z, b4.w};
            #pragma unroll
            for (int i = 0; i < 4; ++i)
                #pragma unroll
                for (int j = 0; j < 4; ++j)
                    acc[i][j] = fmaf(a[i], b[j], acc[i][j]);
        }
    }
    const float th = thr[0];
    #pragma unroll
    for (int i = 0; i < 4; ++i) {
        int t = t0 + ty * 4 + i;
        float m = (scores[(size_t)t * E_NUM + e] > th) ? 1.f : 0.f;
        float4 o;
        o.x = acc[i][0] * m; o.y = acc[i][1] * m;
        o.z = acc[i][2] * m; o.w = acc[i][3] * m;
        *(float4*)&eo[((size_t)t * E_NUM + e) * C_DIM + c0 + tx * 4] = o;
    }
}

// ============================================================================
extern "C" void kernel_launch(void* const* d_in, const int* in_sizes, int n_in,
                              void* d_out, int out_size, void* d_ws, size_t ws_size,
                              hipStream_t stream) {
    const float* x   = (const float*)d_in[0];
    const float* sim = (const float*)d_in[1];
    const float* thr = (const float*)d_in[2];
    const float* W1  = (const float*)d_in[3];
    const float* W2  = (const float*)d_in[4];

    float* out    = (float*)d_out;
    float* fin    = out;
    float* scores = out + (size_t)N_TOK * C_DIM;
    float* eo     = scores + (size_t)N_TOK * E_NUM;
    float* kpt    = eo + (size_t)N_TOK * E_NUM * C_DIM;

    smk_gate2<<<N_TOK / 16, 256, 0, stream>>>(x, sim, thr, scores, kpt);

    const size_t SZ_XS  = 16777216;  // X hi+lo:   32p x 4096 x 128B
    const size_t SZ_W1H = 8388608;   // W1 hi:     16q x 4096 x 128B
    const size_t SZ_W2S = 16777216;  // W2 hi+lo:   8p x 16384 x 128B
    const size_t SZ_HSH = 33554432;  // H hi:  16e x 4q x 4096 x 128B
    const size_t WS_NEED = SZ_XS + SZ_W1H + SZ_W2S + SZ_HSH;  // 75,497,472

    if (ws_size >= WS_NEED) {
        char* Xs  = (char*)d_ws;
        char* W1h = Xs + SZ_XS;
        char* W2s = W1h + SZ_W1H;
        char* Hsh = W2s + SZ_W2S;

        smk_split  <<<2048, 256, 0, stream>>>(x,  Xs,  4096,  7);
        smk_splitBH<<<2048, 256, 0, stream>>>(W1, W1h, 4096,  7);
        smk_split  <<<2048, 256, 0, stream>>>(W2, W2s, 16384, 5);

        dim3 g1(32, 2, 16);
        smk_ffn1_mfma<<<g1, 256, 0, stream>>>(Xs, W1h, Hsh);
        dim3 g2(32, 8, 16);
        smk_ffn2_mfma<<<g2, 256, 0, stream>>>(Hsh, W2s, scores, thr, eo);
    } else {
        const size_t needH = (size_t)N_TOK * E_NUM * I_DIM * sizeof(float);
        if (ws_size >= needH) {
            float* H = (float*)d_ws;
            dim3 g1(N_TOK / BM, I_DIM / BN, E_NUM);
            smk_ffn1<<<g1, 256, 0, stream>>>(x, W1, H, E_NUM, 0);
            dim3 g2(N_TOK / BM, C_DIM / BN, E_NUM);
            smk_ffn2<<<g2, 256, 0, stream>>>(H, W2, scores, thr, eo, E_NUM, 0);
        } else {
            float* H = fin;
            for (int e = 0; e < E_NUM; ++e) {
                dim3 g1(N_TOK / BM, I_DIM / BN, 1);
                smk_ffn1<<<g1, 256, 0, stream>>>(x, W1, H, 1, e);
                dim3 g2(N_TOK / BM, C_DIM / BN, 1);
                smk_ffn2<<<g2, 256, 0, stream>>>(H, W2, scores, thr, eo, 1, e);
            }
        }
    }

    smk_combine<<<(N_TOK * C_DIM / 4) / 256, 256, 0, stream>>>(eo, fin);
}